// Round 1
// baseline (221.492 us; speedup 1.0000x reference)
//
#include <hip/hip_runtime.h>
#include <math.h>

// ---- workspace layout (float offsets) ----
#define WS_MAP      0            // 524288 floats: B x 256 x 256 raw map (pre-rot, pre-norm)
#define WS_SETUP    524288       // 128 floats: 8 batches x 16 (R[9], center[3], shank)
#define WS_POS4     524416       // 40000 floats: 10000 x float4 (x,y,z,pol)
#define WS_ECC      564416       // 10000 floats: ecc per v1 unit
#define WS_PAR4     574416       // 32000 floats: 8000 x float4 (cx, cy, 1/(s^2+eps), w)
#define WS_MAX      606416       // 8 floats: per-b max

#define NB 8
#define NN 1000
#define NV 10000

// Per-batch: rotation matrix, direction, surface-dist bilinear interp, grid center.
__global__ void k_setup(const float* __restrict__ params,
                        const float* __restrict__ start_loc,
                        const float* __restrict__ lut,
                        const float* __restrict__ agrid,
                        const float* __restrict__ bgrid,
                        float* __restrict__ ws) {
    int b = threadIdx.x;
    if (b >= NB) return;
    float alpha = params[b*4+0], beta = params[b*4+1];
    float off   = params[b*4+2], shank = params[b*4+3];
    const float D2R = 0.017453292519943295f;
    float a = alpha*D2R, bb = beta*D2R;
    float ca = cosf(a), sa = sinf(a), cb = cosf(bb), sb = sinf(bb);
    // R = Rx(alpha) @ Ry(beta)
    float r00=cb,      r01=0.f, r02=sb;
    float r10=sa*sb,   r11=ca,  r12=-sa*cb;
    float r20=-ca*sb,  r21=sa,  r22=ca*cb;
    // direction = R @ (0,0,-1) = -col2, normalized
    float dx=-r02, dy=-r12, dz=-r22;
    float inv = rsqrtf(dx*dx+dy*dy+dz*dz);
    dx*=inv; dy*=inv; dz*=inv;
    // bilinear interp of surf dist LUT (37x26), matching reference arithmetic
    float ag0=agrid[0], agN=agrid[36], bg0=bgrid[0], bgN=bgrid[25];
    float an = 2.f*(alpha-ag0)/(agN-ag0+1e-8f) - 1.f;
    float bn = 2.f*(beta -bg0)/(bgN-bg0+1e-8f) - 1.f;
    float ai = fminf(fmaxf((an+1.f)*0.5f*36.f, 0.f), 36.f);
    float bi = fminf(fmaxf((bn+1.f)*0.5f*25.f, 0.f), 25.f);
    int a0 = (int)floorf(ai); a0 = a0<0?0:(a0>36?36:a0);
    int b0 = (int)floorf(bi); b0 = b0<0?0:(b0>25?25:b0);
    int a1 = a0+1>36?36:a0+1;
    int b1 = b0+1>25?25:b0+1;
    float fa = ai - (float)a0, fb = bi - (float)b0;
    float v00=lut[a0*26+b0], v01=lut[a0*26+b1], v10=lut[a1*26+b0], v11=lut[a1*26+b1];
    float sd = v00*(1.f-fa)*(1.f-fb) + v01*(1.f-fa)*fb + v10*fa*(1.f-fb) + v11*fa*fb;
    sd = fmaxf(sd, 1.f);
    float pen = sd - shank*0.5f - off;
    float* o = ws + WS_SETUP + b*16;
    o[0]=r00; o[1]=r01; o[2]=r02; o[3]=r10; o[4]=r11; o[5]=r12;
    o[6]=r20; o[7]=r21; o[8]=r22;
    o[9]  = start_loc[0] + dx*pen;
    o[10] = start_loc[1] + dy*pen;
    o[11] = start_loc[2] + dz*pen;
    o[12] = shank;
}

// Pack v1 data for vectorized streaming: float4(x,y,z,pol) + float(ecc).
__global__ void k_pack(const float* __restrict__ v1_pos,
                       const float* __restrict__ v1_prf,
                       float* __restrict__ ws) {
    int v = blockIdx.x*blockDim.x + threadIdx.x;
    if (v >= NV) return;
    float4* p4 = (float4*)(ws + WS_POS4);
    p4[v] = make_float4(v1_pos[v*3+0], v1_pos[v*3+1], v1_pos[v*3+2], v1_prf[v*3+0]);
    ws[WS_ECC + v] = v1_prf[v*3+1];
}

// One wave per (b,n): stream all 10000 v1 units, reduce wsum / pol / ecc,
// then emit render params {cx, cy, 1/(s^2+eps), weight}.
__global__ __launch_bounds__(256) void k_weights(const float* __restrict__ logits,
                                                 const float* __restrict__ tmpl,
                                                 float* __restrict__ ws) {
    int wid  = blockIdx.x*4 + (threadIdx.x >> 6);   // 2000 blocks x 4 waves = 8000
    int lane = threadIdx.x & 63;
    int b = wid / NN, n = wid % NN;
    const float* st = ws + WS_SETUP + b*16;
    float r00=st[0],r01=st[1],r02=st[2],r10=st[3],r11=st[4],r12=st[5];
    float r20=st[6],r21=st[7],r22=st[8];
    float ccx=st[9],ccy=st[10],ccz=st[11],shank=st[12];
    // centered grid point (template means are analytically 1.8, 1.8, 0.5)
    float gx = tmpl[n*3+0]-1.8f, gy = tmpl[n*3+1]-1.8f, gz = (tmpl[n*3+2]-0.5f)*shank;
    float px = r00*gx + r01*gy + r02*gz + ccx;
    float py = r10*gx + r11*gy + r12*gz + ccy;
    float pz = r20*gx + r21*gy + r22*gz + ccz;
    const float4* p4 = (const float4*)(ws + WS_POS4);
    const float*  ec = ws + WS_ECC;
    float sw=0.f, sp=0.f, se=0.f;
    for (int v = lane; v < NV; v += 64) {
        float4 p = p4[v];
        float e  = ec[v];
        float dx=px-p.x, dy=py-p.y, dz=pz-p.z;
        float d2 = dx*dx + dy*dy + dz*dz;
        float wv = __expf(d2 * (-1.f/4.5f));   // exp(-d2 / (2*1.5^2))
        sw += wv; sp += wv*p.w; se += wv*e;
    }
    #pragma unroll
    for (int m = 32; m >= 1; m >>= 1) {
        sw += __shfl_xor(sw, m, 64);
        sp += __shfl_xor(sp, m, 64);
        se += __shfl_xor(se, m, 64);
    }
    if (lane == 0) {
        float denom = sw + 1e-8f;
        float pol = sp/denom, eccv = se/denom;
        float validity = fminf(sw, 1.f);
        float lg = logits[wid];
        float prob = 1.f/(1.f + __expf(-lg));
        float wgt = prob * validity;
        float ang = pol * 0.017453292519943295f;
        float m1 = 17.3f*(1.f/(eccv+0.75f) - 1.f/(eccv+120.f));
        float minv = 1.f/(fabsf(m1)+1e-8f);
        float sig  = 0.3849001794597506f * minv * 0.5f;   // sqrt(100/675)*m_inv/2
        const float scl = 256.f/90.f;
        float s = fmaxf(sig*scl, 1.f);                    // provably == 1.0 (ecc<=12)
        float invden = 1.f/(s*s + 1e-8f);
        float cxo = eccv*cosf(ang)*scl + 128.f;
        float cyo = eccv*sinf(ang)*scl + 128.f;
        float4* o = (float4*)(ws + WS_PAR4);
        o[wid] = make_float4(cxo, cyo, invden, wgt);
    }
}

// One block per (b,n): 16x16 pixel window around the phosphene center.
// s == 1 => contributions beyond radius 7 are <= e^-49 of center => negligible
// vs absmax threshold 2e-2 after normalization.
__global__ __launch_bounds__(256) void k_render(float* __restrict__ ws) {
    int wid = blockIdx.x;
    const float4* pp = (const float4*)(ws + WS_PAR4);
    float4 p = pp[wid];
    if (p.w < 1e-20f) return;      // uniform across block
    int b  = wid / NN;
    int tx = threadIdx.x & 15, ty = threadIdx.x >> 4;
    int ix = (int)floorf(p.x) - 7 + tx;
    int iy = (int)floorf(p.y) - 7 + ty;
    if (ix < 0 || ix > 255 || iy < 0 || iy > 255) return;
    float dx = (float)ix - p.x, dy = (float)iy - p.y;
    float val = p.w * __expf(-(dx*dx + dy*dy) * p.z);
    atomicAdd(ws + WS_MAP + b*65536 + iy*256 + ix, val);
}

__global__ __launch_bounds__(256) void k_max(float* __restrict__ ws) {
    int b = blockIdx.x;
    const float* m = ws + WS_MAP + b*65536;
    float mx = 0.f;  // map values are >= 0
    for (int i = threadIdx.x; i < 65536; i += 256) mx = fmaxf(mx, m[i]);
    __shared__ float red[256];
    red[threadIdx.x] = mx;
    __syncthreads();
    for (int s2 = 128; s2 > 0; s2 >>= 1) {
        if (threadIdx.x < s2) red[threadIdx.x] = fmaxf(red[threadIdx.x], red[threadIdx.x+s2]);
        __syncthreads();
    }
    if (threadIdx.x == 0) ws[WS_MAX + b] = red[0];
}

// rot90(k=1, axes=(-2,-1)): out[b,i,j] = raw[b, j, 255-i]; then normalize.
__global__ __launch_bounds__(256) void k_final(const float* __restrict__ ws,
                                               float* __restrict__ out) {
    int idx = blockIdx.x*256 + threadIdx.x;   // 524288 total
    int b = idx >> 16, r = (idx >> 8) & 255, c = idx & 255;
    float mv = ws[WS_MAX + b];
    out[idx] = ws[WS_MAP + b*65536 + c*256 + (255 - r)] / (mv + 1e-8f);
}

extern "C" void kernel_launch(void* const* d_in, const int* in_sizes, int n_in,
                              void* d_out, int out_size, void* d_ws, size_t ws_size,
                              hipStream_t stream) {
    const float* params    = (const float*)d_in[0];
    const float* logits    = (const float*)d_in[1];
    const float* v1_pos    = (const float*)d_in[2];
    const float* v1_prf    = (const float*)d_in[3];
    const float* start_loc = (const float*)d_in[4];
    const float* lut       = (const float*)d_in[5];
    const float* agrid     = (const float*)d_in[6];
    const float* bgrid     = (const float*)d_in[7];
    const float* tmpl      = (const float*)d_in[8];
    float* ws  = (float*)d_ws;
    float* out = (float*)d_out;

    hipMemsetAsync(d_ws, 0, 524288*sizeof(float), stream);   // zero the map (ws is re-poisoned)
    k_setup  <<<1,    64,  0, stream>>>(params, start_loc, lut, agrid, bgrid, ws);
    k_pack   <<<40,   256, 0, stream>>>(v1_pos, v1_prf, ws);
    k_weights<<<2000, 256, 0, stream>>>(logits, tmpl, ws);
    k_render <<<8000, 256, 0, stream>>>(ws);
    k_max    <<<8,    256, 0, stream>>>(ws);
    k_final  <<<2048, 256, 0, stream>>>(ws, out);
}

// Round 2
// 145.851 us; speedup vs baseline: 1.5186x; 1.5186x over previous
//
#include <hip/hip_runtime.h>
#include <math.h>

// ---- workspace layout (float offsets) ----
// WS_MAP doubles as the k_weights partial buffer (16*8192 float4 = 2 MB exactly);
// partials are consumed by k_params BEFORE the map memset (stream-ordered).
#define WS_MAP      0            // 524288 floats: B x 256 x 256 raw map / weight partials
#define WS_PART     0
#define WS_POS4     524288       // 40000 floats: 10000 x float4 (x,y,z,pol)
#define WS_ECC      564288       // 10000 floats: ecc per v1 unit
#define WS_EPOS     574288       // 32768 floats: 8192 x float4 (px,py,pz,prob)
#define WS_PAR4     607056       // 32768 floats: 8192 x float4 (cx,cy,1/(s^2+eps),w)
#define WS_SETUP    639824       // 128 floats: 8 x 16 (R[9], center[3], shank)
#define WS_MAX      639952       // 8 floats

#define NB 8
#define NN 1000
#define NV 10000
#define NE 8192                  // padded electrode count (8*1000 -> 8192)
#define NCHUNK 16
#define CHUNK 625                // 10000 / 16

// Per-batch: rotation matrix, direction, surface-dist bilinear interp, grid center.
__global__ void k_setup(const float* __restrict__ params,
                        const float* __restrict__ start_loc,
                        const float* __restrict__ lut,
                        const float* __restrict__ agrid,
                        const float* __restrict__ bgrid,
                        float* __restrict__ ws) {
    int b = threadIdx.x;
    if (b >= NB) return;
    float alpha = params[b*4+0], beta = params[b*4+1];
    float off   = params[b*4+2], shank = params[b*4+3];
    const float D2R = 0.017453292519943295f;
    float a = alpha*D2R, bb = beta*D2R;
    float ca = cosf(a), sa = sinf(a), cb = cosf(bb), sb = sinf(bb);
    // R = Rx(alpha) @ Ry(beta)
    float r00=cb,      r01=0.f, r02=sb;
    float r10=sa*sb,   r11=ca,  r12=-sa*cb;
    float r20=-ca*sb,  r21=sa,  r22=ca*cb;
    // direction = R @ (0,0,-1) = -col2, normalized
    float dx=-r02, dy=-r12, dz=-r22;
    float inv = rsqrtf(dx*dx+dy*dy+dz*dz);
    dx*=inv; dy*=inv; dz*=inv;
    // bilinear interp of 37x26 LUT, matching reference arithmetic
    float ag0=agrid[0], agN=agrid[36], bg0=bgrid[0], bgN=bgrid[25];
    float an = 2.f*(alpha-ag0)/(agN-ag0+1e-8f) - 1.f;
    float bn = 2.f*(beta -bg0)/(bgN-bg0+1e-8f) - 1.f;
    float ai = fminf(fmaxf((an+1.f)*0.5f*36.f, 0.f), 36.f);
    float bi = fminf(fmaxf((bn+1.f)*0.5f*25.f, 0.f), 25.f);
    int a0 = (int)floorf(ai); a0 = a0<0?0:(a0>36?36:a0);
    int b0 = (int)floorf(bi); b0 = b0<0?0:(b0>25?25:b0);
    int a1 = a0+1>36?36:a0+1;
    int b1 = b0+1>25?25:b0+1;
    float fa = ai - (float)a0, fb = bi - (float)b0;
    float v00=lut[a0*26+b0], v01=lut[a0*26+b1], v10=lut[a1*26+b0], v11=lut[a1*26+b1];
    float sd = v00*(1.f-fa)*(1.f-fb) + v01*(1.f-fa)*fb + v10*fa*(1.f-fb) + v11*fa*fb;
    sd = fmaxf(sd, 1.f);
    float pen = sd - shank*0.5f - off;
    float* o = ws + WS_SETUP + b*16;
    o[0]=r00; o[1]=r01; o[2]=r02; o[3]=r10; o[4]=r11; o[5]=r12;
    o[6]=r20; o[7]=r21; o[8]=r22;
    o[9]  = start_loc[0] + dx*pen;
    o[10] = start_loc[1] + dy*pen;
    o[11] = start_loc[2] + dz*pen;
    o[12] = shank;
}

// Pack v1 data (float4 + ecc) AND precompute per-electrode positions + sigmoid(logit).
__global__ __launch_bounds__(256) void k_packepos(const float* __restrict__ v1_pos,
                                                  const float* __restrict__ v1_prf,
                                                  const float* __restrict__ logits,
                                                  const float* __restrict__ tmpl,
                                                  float* __restrict__ ws) {
    int t = blockIdx.x*256 + threadIdx.x;    // 40 blocks -> 10240 threads
    if (t < NV) {
        float4* p4 = (float4*)(ws + WS_POS4);
        p4[t] = make_float4(v1_pos[t*3+0], v1_pos[t*3+1], v1_pos[t*3+2], v1_prf[t*3+0]);
        ws[WS_ECC + t] = v1_prf[t*3+1];
    }
    if (t < NE) {
        float4* ep = (float4*)(ws + WS_EPOS);
        if (t < NB*NN) {
            int b = t / NN, n = t % NN;
            const float* st = ws + WS_SETUP + b*16;
            // centered grid point (template means are analytically 1.8, 1.8, 0.5)
            float gx = tmpl[n*3+0]-1.8f, gy = tmpl[n*3+1]-1.8f;
            float gz = (tmpl[n*3+2]-0.5f)*st[12];
            float px = st[0]*gx + st[1]*gy + st[2]*gz + st[9];
            float py = st[3]*gx + st[4]*gy + st[5]*gz + st[10];
            float pz = st[6]*gx + st[7]*gy + st[8]*gz + st[11];
            float prob = 1.f/(1.f + __expf(-logits[t]));
            ep[t] = make_float4(px, py, pz, prob);
        } else {
            ep[t] = make_float4(1e9f, 1e9f, 1e9f, 0.f);  // far away -> exp(-big)=0
        }
    }
}

// LDS-staged soft-match: block = one V-chunk x 256 electrodes (one per thread).
// v1 chunk is broadcast-read from LDS (conflict-free); partial (sw,sp,se) per
// (chunk, electrode) goes to WS_PART.
__global__ __launch_bounds__(256) void k_weights(float* __restrict__ ws) {
    __shared__ float4 sp4[CHUNK];
    __shared__ float  sec[CHUNK];
    int g  = blockIdx.x;            // 512 = 16 chunks x 32 electrode groups
    int c  = g >> 5;
    int eg = g & 31;
    int t  = threadIdx.x;
    const float4* p4 = (const float4*)(ws + WS_POS4);
    const float*  ec = ws + WS_ECC;
    int v0 = c*CHUNK;
    for (int i = t; i < CHUNK; i += 256) { sp4[i] = p4[v0+i]; sec[i] = ec[v0+i]; }
    __syncthreads();
    int e = eg*256 + t;
    float4 P = ((const float4*)(ws + WS_EPOS))[e];
    float sw = 0.f, sp = 0.f, se = 0.f;
    #pragma unroll 5
    for (int i = 0; i < CHUNK; ++i) {
        float4 q = sp4[i];
        float dx = P.x-q.x, dy = P.y-q.y, dz = P.z-q.z;
        float d2 = dx*dx + dy*dy + dz*dz;
        float wv = __expf(d2 * -0.22222222f);    // exp(-d2 / (2*1.5^2))
        sw += wv; sp += wv*q.w; se += wv*sec[i];
    }
    ((float4*)(ws + WS_PART))[c*NE + e] = make_float4(sw, sp, se, 0.f);
}

// Reduce chunk partials, compute render params {cx, cy, 1/(s^2+eps), weight}.
__global__ __launch_bounds__(256) void k_params(float* __restrict__ ws) {
    int e = blockIdx.x*256 + threadIdx.x;    // 32 blocks -> 8192
    const float4* part = (const float4*)(ws + WS_PART);
    float sw = 0.f, sp = 0.f, se = 0.f;
    #pragma unroll
    for (int c = 0; c < NCHUNK; ++c) {
        float4 p = part[c*NE + e];
        sw += p.x; sp += p.y; se += p.z;
    }
    if (e < NB) ws[WS_MAX + e] = 0.f;        // init for atomicMax (runs before k_max)
    if (e >= NB*NN) return;
    float denom = sw + 1e-8f;
    float pol = sp/denom, eccv = se/denom;
    float validity = fminf(sw, 1.f);
    float prob = ((const float4*)(ws + WS_EPOS))[e].w;
    float wgt = prob * validity;
    float ang = pol * 0.017453292519943295f;
    float m1 = 17.3f*(1.f/(eccv+0.75f) - 1.f/(eccv+120.f));
    float minv = 1.f/(fabsf(m1)+1e-8f);
    float sig  = 0.3849001794597506f * minv * 0.5f;   // sqrt(100/675)*m_inv/2
    const float scl = 256.f/90.f;
    float s = fmaxf(sig*scl, 1.f);                    // provably == 1.0 (ecc<=12)
    float invden = 1.f/(s*s + 1e-8f);
    ((float4*)(ws + WS_PAR4))[e] =
        make_float4(eccv*cosf(ang)*scl + 128.f, eccv*sinf(ang)*scl + 128.f, invden, wgt);
}

// One block per electrode: 16x16 window; skip atomics where exp term < 1.6e-9
// (d2 > 20.25) — truncation <= 1000*1.6e-9 per pixel, far below the 2e-2 threshold.
__global__ __launch_bounds__(256) void k_render(float* __restrict__ ws) {
    int wid = blockIdx.x;
    float4 p = ((const float4*)(ws + WS_PAR4))[wid];
    if (p.w <= 0.f) return;                 // uniform across block
    int b  = wid / NN;
    int tx = threadIdx.x & 15, ty = threadIdx.x >> 4;
    int ix = (int)floorf(p.x) - 7 + tx;
    int iy = (int)floorf(p.y) - 7 + ty;
    if (ix < 0 || ix > 255 || iy < 0 || iy > 255) return;
    float dx = (float)ix - p.x, dy = (float)iy - p.y;
    float d2 = dx*dx + dy*dy;
    if (d2 > 20.25f) return;
    float val = p.w * __expf(-d2 * p.z);
    atomicAdd(ws + WS_MAP + b*65536 + iy*256 + ix, val);
}

// Per-b max via 16 blocks/b + uint atomicMax (valid for non-negative floats).
__global__ __launch_bounds__(256) void k_max(float* __restrict__ ws) {
    int g = blockIdx.x;                     // 128
    int b = g >> 4;
    const float* m = ws + WS_MAP + b*65536 + (g & 15)*4096;
    float mx = 0.f;
    for (int i = threadIdx.x; i < 4096; i += 256) mx = fmaxf(mx, m[i]);
    #pragma unroll
    for (int s2 = 32; s2 >= 1; s2 >>= 1) mx = fmaxf(mx, __shfl_xor(mx, s2, 64));
    __shared__ float red[4];
    if ((threadIdx.x & 63) == 0) red[threadIdx.x >> 6] = mx;
    __syncthreads();
    if (threadIdx.x == 0) {
        mx = fmaxf(fmaxf(red[0], red[1]), fmaxf(red[2], red[3]));
        atomicMax((unsigned int*)(ws + WS_MAX + b), __float_as_uint(mx));
    }
}

// rot90 + normalize via padded LDS tile: out[b,r,c] = raw[b, c, 255-r] / max.
__global__ __launch_bounds__(256) void k_final(const float* __restrict__ ws,
                                               float* __restrict__ out) {
    __shared__ float tile[32][33];
    int g  = blockIdx.x;                    // 512 = 8 b x 64 tiles
    int b  = g >> 6;
    int t6 = g & 63;
    int r0 = (t6 >> 3) * 32;
    int c0 = (t6 & 7) * 32;
    int ic0 = 224 - r0;                     // input col start = 255 - r0 - 31
    int j  = threadIdx.x & 31;
    int i0 = threadIdx.x >> 5;
    const float* m = ws + WS_MAP + b*65536;
    #pragma unroll
    for (int p = 0; p < 4; ++p) {
        int i = i0 + p*8;
        tile[i][j] = m[(c0+i)*256 + ic0 + j];   // coalesced load
    }
    __syncthreads();
    float inv = 1.f/(ws[WS_MAX + b] + 1e-8f);
    #pragma unroll
    for (int p = 0; p < 4; ++p) {
        int k = i0 + p*8;
        out[b*65536 + (r0+k)*256 + c0 + j] = tile[j][31-k] * inv;  // coalesced store
    }
}

extern "C" void kernel_launch(void* const* d_in, const int* in_sizes, int n_in,
                              void* d_out, int out_size, void* d_ws, size_t ws_size,
                              hipStream_t stream) {
    const float* params    = (const float*)d_in[0];
    const float* logits    = (const float*)d_in[1];
    const float* v1_pos    = (const float*)d_in[2];
    const float* v1_prf    = (const float*)d_in[3];
    const float* start_loc = (const float*)d_in[4];
    const float* lut       = (const float*)d_in[5];
    const float* agrid     = (const float*)d_in[6];
    const float* bgrid     = (const float*)d_in[7];
    const float* tmpl      = (const float*)d_in[8];
    float* ws  = (float*)d_ws;
    float* out = (float*)d_out;

    k_setup   <<<1,    64,  0, stream>>>(params, start_loc, lut, agrid, bgrid, ws);
    k_packepos<<<40,   256, 0, stream>>>(v1_pos, v1_prf, logits, tmpl, ws);
    k_weights <<<512,  256, 0, stream>>>(ws);
    k_params  <<<32,   256, 0, stream>>>(ws);
    // map region (== partial region) is free only after k_params consumed it
    hipMemsetAsync(d_ws, 0, 524288*sizeof(float), stream);
    k_render  <<<8000, 256, 0, stream>>>(ws);
    k_max     <<<128,  256, 0, stream>>>(ws);
    k_final   <<<512,  256, 0, stream>>>(ws, out);
}